// Round 10
// baseline (16.511 us; speedup 1.0000x reference)
//
#include <hip/hip_runtime.h>
#include <math.h>
#include <stdint.h>

// EdgeLayer: out[b,o] = min_j ( x[b,j] + mask[o,j] ),
// mask = bernoulli(km, softmax(edges)[...,1]), JAX partitionable threefry,
// 32-bit draws = bits1 ^ bits2.  (Bit-exact, proven R4-R9: absmax = 0.)
//
// Identity (proven on-data R6-R9):
//   out[b,o] = min( g_b + 1.0f, min{ x[b,j] : x[b,j] < g_b+1, mask[o,j]=0 } )
// with g_b = min_j x[b,j].  ~11 candidates/row.
//
// R10: max-occupancy probe walk.  Block = 256 thr = ONE row x 32 o-tasks,
// PW=8 lanes/task -> one ballot round covers the 8 smallest candidates
// (P(second round) ~ 0.4%).  Grid = 32 rows x 64 o-groups = 2048 blocks
// -> 8 blocks/CU = 32 waves/CU (hardware max), 2x R9's latency hiding.
// B=32, IN_F=2048, OUT_F=2048, f32.

#define BATCH 32
#define INFEAT 2048
#define OUTFEAT 2048
#define CAP 64        // P(cnt>64) ~ 1e-30; exact dense fallback kept anyway
#define PW 8          // probe width: lanes per (b,o) task
#define TASKS_PB 32   // o-values per block = 256/PW
#define OGROUPS (OUTFEAT / TASKS_PB)   // 64

struct U2 { uint32_t a, b; };

__host__ __device__ constexpr uint32_t rotl32c(uint32_t x, int r) {
  return (x << r) | (x >> (32 - r));
}

// Exact JAX/Random123 threefry2x32: 20 rounds, both output words.
__host__ __device__ constexpr U2 tf2x32(uint32_t k0, uint32_t k1,
                                        uint32_t x0, uint32_t x1) {
  const uint32_t ks2 = k0 ^ k1 ^ 0x1BD11BDAu;
#define RND(r) { x0 += x1; x1 = rotl32c(x1, (r)); x1 ^= x0; }
  x0 += k0; x1 += k1;
  RND(13) RND(15) RND(26) RND(6)
  x0 += k1; x1 += ks2 + 1u;
  RND(17) RND(29) RND(16) RND(24)
  x0 += ks2; x1 += k0 + 2u;
  RND(13) RND(15) RND(26) RND(6)
  x0 += k0; x1 += k1 + 3u;
  RND(17) RND(29) RND(16) RND(24)
  x0 += k1; x1 += ks2 + 4u;
  RND(13) RND(15) RND(26) RND(6)
  x0 += ks2; x1 += k0 + 5u;
#undef RND
  return U2{x0, x1};
}

// km = split(key(42))[0] under partitionable split: full (y0,y1) of tf(key;0,0)
constexpr U2 KM = tf2x32(0u, 42u, 0u, 0u);

__device__ __forceinline__ float u01_from_bits(uint32_t bits) {
  return __uint_as_float((bits >> 9) | 0x3f800000u) - 1.0f;
}

// softmax(edges,-1)[...,1] in f32; single nontrivial exp via double
// (bit-exact vs reference, proven R4).
__device__ __forceinline__ float prob_edge(float e0, float e1) {
  const float d = e1 - e0;
  const float a = -fabsf(d);
  const float t = (float)exp((double)a);
  return (d >= 0.0f) ? (1.0f / (t + 1.0f)) : (t / (1.0f + t));
}

// Bernoulli mask bit for (o, j): true = edge present (mask adds +1.0f)
__device__ __forceinline__ bool edge_bit(int o, int j, float e0, float e1) {
  const uint32_t n = (uint32_t)(o * INFEAT + j);
  const U2 y = tf2x32(KM.a, KM.b, 0u, n);
  return u01_from_bits(y.a ^ y.b) < prob_edge(e0, e1);
}

__global__ __launch_bounds__(256) void edge_min_probe(
    const float* __restrict__ x,      // [32][2048]
    const float* __restrict__ edges,  // [2048][2048][2]
    float* __restrict__ out) {        // [32][2048]
  __shared__ float sred[4];
  __shared__ int   s_cnt;
  __shared__ float sx [CAP];   // unsorted candidates
  __shared__ int   sjc[CAP];
  __shared__ float ssx[CAP];   // rank-sorted candidates
  __shared__ int   ssj[CAP];

  const int tid  = threadIdx.x;
  const int lane = tid & 63;
  const int wv   = tid >> 6;
  const int b    = blockIdx.x >> 6;            // 0..31 (row)
  const int og   = blockIdx.x & (OGROUPS - 1); // 0..63 (o-group)

  if (tid == 0) s_cnt = 0;

  // ---- prep: row min (256 thr x 8 elems, coalesced float4) ----
  const float4* x4 = (const float4*)x;
  const float4 v0 = x4[b * (INFEAT/4) + tid*2];
  const float4 v1 = x4[b * (INFEAT/4) + tid*2 + 1];
  float lm = fminf(fminf(fminf(v0.x, v0.y), fminf(v0.z, v0.w)),
                   fminf(fminf(v1.x, v1.y), fminf(v1.z, v1.w)));
#pragma unroll
  for (int off = 32; off > 0; off >>= 1)
    lm = fminf(lm, __shfl_xor(lm, off, 64));
  if (lane == 0) sred[wv] = lm;
  __syncthreads();
  const float thr = fminf(fminf(sred[0], sred[1]),
                          fminf(sred[2], sred[3])) + 1.0f;  // g_b + 1, exact

  // ---- candidate collect (thread tid owns columns tid*8 .. tid*8+7) ----
  const float c[8] = {v0.x, v0.y, v0.z, v0.w, v1.x, v1.y, v1.z, v1.w};
#pragma unroll
  for (int q = 0; q < 8; ++q) {
    if (c[q] < thr) {                        // ~11 hits per row
      const int idx = atomicAdd(&s_cnt, 1);
      if (idx < CAP) { sx[idx] = c[q]; sjc[idx] = tid*8 + q; }
    }
  }
  __syncthreads();
  const int cnt_raw = s_cnt;
  const int cnt = min(cnt_raw, CAP);

  // ---- rank sort (deterministic: tie-break by column index) ----
  if (tid < cnt) {
    const float xi = sx[tid];
    const int   ji = sjc[tid];
    int rank = 0;
    for (int k = 0; k < cnt; ++k) {
      const float xk = sx[k];
      const int   jk = sjc[k];
      rank += (xk < xi) || (xk == xi && jk < ji);
    }
    ssx[rank] = xi;
    ssj[rank] = ji;
  }
  __syncthreads();

  // ---- probe-parallel walk: 8 lanes per o, ballot first-zero ----
  const int task = tid >> 3;                 // 0..31
  const int pc   = tid & 7;                  // probe slot within group
  const int o    = og * TASKS_PB + task;
  const float2* e2 = (const float2*)edges;
  float res;

  if (cnt_raw > CAP) {
    // exact dense fallback -- statistically unreachable, kept for rigor
    float m = INFINITY;
    for (int j = pc; j < INFEAT; j += PW) {
      const float2 e = e2[o * INFEAT + j];
      const float bit = edge_bit(o, j, e.x, e.y) ? 1.0f : 0.0f;
      m = fminf(m, x[b * INFEAT + j] + bit);
    }
    m = fminf(m, __shfl_xor(m, 1, 64));
    m = fminf(m, __shfl_xor(m, 2, 64));
    m = fminf(m, __shfl_xor(m, 4, 64));
    res = m;
  } else {
    int widx = -1;
    for (int r = 0; r * PW < cnt; ++r) {
      const int idx = r * PW + pc;
      const bool act = idx < cnt;
      const int cj = act ? ssj[idx] : 0;         // j=0 safe when inactive
      const float2 e = e2[o * INFEAT + cj];      // gather, 1 load/lane
      const bool bit = act ? edge_bit(o, cj, e.x, e.y) : true;
      const unsigned long long zb = __ballot(!bit);
      const uint32_t byte = (uint32_t)(zb >> (lane & 56)) & 0xFFu;
      if (byte) { widx = r * PW + (__ffs((int)byte) - 1); break; }
    }
    // first unmasked candidate's x, else g+1 (all candidates masked)
    res = (widx >= 0) ? fminf(ssx[widx], thr) : thr;
  }
  if (pc == 0) out[b * OUTFEAT + o] = res;
}

extern "C" void kernel_launch(void* const* d_in, const int* in_sizes, int n_in,
                              void* d_out, int out_size, void* d_ws, size_t ws_size,
                              hipStream_t stream) {
  const float* x     = (const float*)d_in[0];   // 32*2048
  const float* edges = (const float*)d_in[1];   // 2048*2048*2
  float* out = (float*)d_out;                   // 32*2048
  (void)in_sizes; (void)n_in; (void)out_size; (void)d_ws; (void)ws_size;

  // grid: 32 rows x 64 o-groups = 2048 blocks, 256 threads each
  hipLaunchKernelGGL(edge_min_probe, dim3(BATCH * OGROUPS), dim3(256),
                     0, stream, x, edges, out);
}